// Round 1
// baseline (638.282 us; speedup 1.0000x reference)
//
#include <hip/hip_runtime.h>

typedef float f32x4 __attribute__((ext_vector_type(4)));
typedef short s16x8 __attribute__((ext_vector_type(8)));

#define NB 4
#define CIN 128
#define COUT 128
#define NT 16
#define NH 64
#define NW 64
#define NTAP 27
#define KTOT (CIN * NTAP)   // 3456

#define HB 4                // h-rows per block
#define SF_T 3
#define SF_H (HB + 2)       // 6
#define SF_W (NW + 2)       // 66
#define IPAD 40             // 32 i + 8 pad (u16) -> 80B row, conflict-light stride
#define SPAT (SF_T * SF_H * SF_W)  // 1188

__device__ __forceinline__ unsigned short f32_to_bf16(float f) {
    unsigned int u = __builtin_bit_cast(unsigned int, f);
    u += 0x7FFFu + ((u >> 16) & 1u);   // round-to-nearest-even
    return (unsigned short)(u >> 16);
}

// Kernel 1: per-(b,o) weight modulation + demodulation -> bf16 [b][tap][o][i]
__global__ __launch_bounds__(256) void modw_kernel(
    const float* __restrict__ cond,      // [4][128]
    const float* __restrict__ weights,   // [128][128][3][3][3]
    unsigned short* __restrict__ wmod)   // [4][27][128][128] bf16 bits
{
    int bo = blockIdx.x;
    int b = bo >> 7;
    int o = bo & 127;
    int tid = threadIdx.x;
    __shared__ float red[256];
    __shared__ float s_scale;
    const float* wrow = weights + o * KTOT;
    const float* cb = cond + b * CIN;

    float acc = 0.f;
    for (int idx = tid; idx < KTOT; idx += 256) {
        int i = idx / NTAP;
        float v = wrow[idx] * (cb[i] + 1.0f);
        acc += v * v;
    }
    red[tid] = acc;
    __syncthreads();
    #pragma unroll
    for (int s = 128; s > 0; s >>= 1) {
        if (tid < s) red[tid] += red[tid + s];
        __syncthreads();
    }
    if (tid == 0) s_scale = 1.0f / sqrtf(fmaxf(red[0], 1e-8f));
    __syncthreads();
    float scale = s_scale;

    for (int idx = tid; idx < KTOT; idx += 256) {
        int i = idx / NTAP;
        int tap = idx - i * NTAP;
        float v = wrow[idx] * (cb[i] + 1.0f) * scale;
        wmod[(((b * NTAP + tap) * COUT + o) * CIN) + i] = f32_to_bf16(v);
    }
}

// Kernel 2: implicit-GEMM conv. Block = (b, t, 4 h-rows), out tile 128o x 256pix.
__global__ __launch_bounds__(512) void conv_kernel(
    const float* __restrict__ fmap,        // [4][128][16][64][64]
    const unsigned short* __restrict__ wmod, // [4][27][128][128] bf16
    float* __restrict__ out)               // [4][128][16][64][64]
{
    __shared__ unsigned short sF[SPAT * IPAD];     // 47520 u16 = 95040 B, [t'][h'][w'][i32]
    __shared__ unsigned short sW[2][COUT * IPAD];  // 2 x 10240 B, [o][i32]

    int bid = blockIdx.x;
    int h0 = (bid & 15) * HB;
    int t0 = (bid >> 4) & 15;
    int b  = bid >> 8;

    int tid = threadIdx.x;
    int wv = tid >> 6;
    int l  = tid & 63;
    int lo = l & 15;
    int hi = l >> 4;
    int obase = (wv & 1) * 64;   // o-half per wave
    int r = wv >> 1;             // h-row (0..3) per wave

    int s_ii = tid >> 4;         // staging: input channel within chunk (0..31)
    int s_ws = tid & 15;         // staging: spatial strider

    f32x4 acc[4][4];
    #pragma unroll
    for (int a = 0; a < 4; ++a)
        #pragma unroll
        for (int p = 0; p < 4; ++p)
            acc[a][p] = f32x4{0.f, 0.f, 0.f, 0.f};

    int tap = 0, ic = 0;
    for (int ks = 0; ks < 108; ++ks) {
        if (tap == 0) {
            if (ks) __syncthreads();   // all reads of sF for prev chunk done
            // stage fmap chunk ic: [3t][6h][66w][32i] bf16, zero-padded halos
            const float* fbase = fmap + (size_t)((b * CIN + ic * 32 + s_ii) * NT) * (NH * NW);
            for (int e = s_ws; e < SPAT; e += 16) {
                int wl = e % SF_W;
                int rr = e / SF_W;
                int hl = rr % SF_H;
                int tl = rr / SF_H;
                int ts = t0 + tl - 2;        // causal: t-2..t
                int hs = h0 + hl - 1;
                int wsrc = wl - 1;
                float v = 0.f;
                if (ts >= 0 && (unsigned)hs < NH && (unsigned)wsrc < NW)
                    v = fbase[(ts * NH + hs) * NW + wsrc];
                sF[e * IPAD + s_ii] = f32_to_bf16(v);
            }
            if (ks == 0) {  // prologue weight stage into buf 0
                int o = tid >> 2, q = tid & 3;
                const unsigned short* src =
                    wmod + (((b * NTAP + 0) * COUT + o) * CIN) + q * 8;
                *reinterpret_cast<uint4*>(&sW[0][o * IPAD + q * 8]) =
                    *reinterpret_cast<const uint4*>(src);
            }
        }
        __syncthreads();   // sF + sW[ks&1] ready; prev reads of sW[ks^1] done

        if (ks + 1 < 108) {   // stage next k-step's weights into other buffer
            int ksn = ks + 1;
            int icn = ksn / 27;
            int tapn = ksn - icn * 27;
            int o = tid >> 2, q = tid & 3;
            const unsigned short* src =
                wmod + (((b * NTAP + tapn) * COUT + o) * CIN) + icn * 32 + q * 8;
            *reinterpret_cast<uint4*>(&sW[ksn & 1][o * IPAD + q * 8]) =
                *reinterpret_cast<const uint4*>(src);
        }

        int kt = tap / 9;
        int rem = tap - kt * 9;
        int kh = rem / 3;
        int kw = rem - kh * 3;

        s16x8 af[4], bfr[4];
        #pragma unroll
        for (int a = 0; a < 4; ++a) {
            int o = obase + a * 16 + lo;
            af[a] = *reinterpret_cast<const s16x8*>(&sW[ks & 1][o * IPAD + hi * 8]);
        }
        #pragma unroll
        for (int p = 0; p < 4; ++p) {
            int sp = (kt * SF_H + (r + kh)) * SF_W + (p * 16 + lo + kw);
            bfr[p] = *reinterpret_cast<const s16x8*>(&sF[sp * IPAD + hi * 8]);
        }
        #pragma unroll
        for (int a = 0; a < 4; ++a)
            #pragma unroll
            for (int p = 0; p < 4; ++p)
                acc[a][p] = __builtin_amdgcn_mfma_f32_16x16x32_bf16(
                    af[a], bfr[p], acc[a][p], 0, 0, 0);

        if (++tap == 27) { tap = 0; ++ic; }
    }

    // epilogue: D row = (lane>>4)*4 + reg, col = lane&15 (verified m89/m91)
    int h = h0 + r;
    #pragma unroll
    for (int a = 0; a < 4; ++a) {
        #pragma unroll
        for (int reg = 0; reg < 4; ++reg) {
            int o = obase + a * 16 + hi * 4 + reg;
            float* orow = out + ((((size_t)b * COUT + o) * NT + t0) * NH + h) * NW;
            #pragma unroll
            for (int p = 0; p < 4; ++p)
                orow[p * 16 + lo] = acc[a][p][reg];
        }
    }
}

extern "C" void kernel_launch(void* const* d_in, const int* in_sizes, int n_in,
                              void* d_out, int out_size, void* d_ws, size_t ws_size,
                              hipStream_t stream) {
    (void)in_sizes; (void)n_in; (void)out_size; (void)ws_size;
    const float* fmap    = (const float*)d_in[0];
    const float* cond    = (const float*)d_in[1];
    const float* weights = (const float*)d_in[2];
    float* outp = (float*)d_out;
    unsigned short* wmod = (unsigned short*)d_ws;  // 4*27*128*128*2B = 3.54 MB

    modw_kernel<<<dim3(NB * COUT), dim3(256), 0, stream>>>(cond, weights, wmod);
    conv_kernel<<<dim3(NB * NT * (NH / HB)), dim3(512), 0, stream>>>(fmap, wmod, outp);
}

// Round 2
// 298.644 us; speedup vs baseline: 2.1373x; 2.1373x over previous
//
#include <hip/hip_runtime.h>

typedef float f32x4 __attribute__((ext_vector_type(4)));
typedef short s16x8 __attribute__((ext_vector_type(8)));

#define NB 4
#define CIN 128
#define COUT 128
#define NT 16
#define NH 64
#define NW 64
#define NTAP 27
#define KTOT (CIN * NTAP)   // 3456

// ---------- big-path geometry ----------
#define FT_H 66
#define FT_W 66
#define WMOD_BYTES (NB * NTAP * COUT * CIN * 2)              // 3,538,944
#define FT_U16 ((size_t)NB * NT * FT_H * FT_W * CIN)         // 35,684,352
#define FT_BYTES (FT_U16 * 2)                                // 71,368,704
#define WS_NEED ((size_t)WMOD_BYTES + FT_BYTES)

// conv2 tile: 2 t x 4 h x 64 w output, 128 o
#define SFT 4
#define SFH 6
#define SFW 72                       // 66 used + 6 pad (keeps rows 8-pixel aligned for swizzle)
#define SFPX (SFT * SFH * SFW)       // 1728 pixels, 64 B each
#define SF_SLOTS (SFPX * 4)          // 6912 16B slots
#define SW_U16 (COUT * 32)           // 4096 u16 = 8 KB per weight buffer

__device__ __forceinline__ unsigned short f32_to_bf16(float f) {
    unsigned int u = __builtin_bit_cast(unsigned int, f);
    u += 0x7FFFu + ((u >> 16) & 1u);   // round-to-nearest-even
    return (unsigned short)(u >> 16);
}

__device__ __forceinline__ void gload16(const void* g, void* l) {
    __builtin_amdgcn_global_load_lds(
        (const __attribute__((address_space(1))) unsigned int*)g,
        (__attribute__((address_space(3))) unsigned int*)l, 16, 0, 0);
}

// ---------------- Kernel 1: weight modulation + demodulation ----------------
// Writes bf16 [b][tap][o][128ch], channel-group position XOR-swizzled by
// ((o>>1)&3) when swz!=0 (to make conv A-fragment ds_reads bank-conflict-free).
__global__ __launch_bounds__(256) void modw_kernel(
    const float* __restrict__ cond,
    const float* __restrict__ weights,
    unsigned short* __restrict__ wmod,
    int swz)
{
    int bo = blockIdx.x;
    int b = bo >> 7;
    int o = bo & 127;
    int tid = threadIdx.x;
    __shared__ float red[256];
    __shared__ float s_scale;
    const float* wrow = weights + o * KTOT;
    const float* cb = cond + b * CIN;

    float acc = 0.f;
    for (int idx = tid; idx < KTOT; idx += 256) {
        int i = idx / NTAP;
        float v = wrow[idx] * (cb[i] + 1.0f);
        acc += v * v;
    }
    red[tid] = acc;
    __syncthreads();
    #pragma unroll
    for (int s = 128; s > 0; s >>= 1) {
        if (tid < s) red[tid] += red[tid + s];
        __syncthreads();
    }
    if (tid == 0) s_scale = 1.0f / sqrtf(fmaxf(red[0], 1e-8f));
    __syncthreads();
    float scale = s_scale;
    int sw_o = swz ? ((o >> 1) & 3) : 0;

    for (int idx = tid; idx < KTOT; idx += 256) {
        int i = idx / NTAP;
        int tap = idx - i * NTAP;
        float v = wrow[idx] * (cb[i] + 1.0f) * scale;
        int pos = (i & 0x60) | ((((i >> 3) & 3) ^ sw_o) << 3) | (i & 7);
        wmod[(((b * NTAP + tap) * COUT + o) * CIN) + pos] = f32_to_bf16(v);
    }
}

// ---------------- Kernel 2: zero h/w borders of fmapT ----------------
__global__ void border_kernel(unsigned short* __restrict__ fmapT) {
    int idx = blockIdx.x * blockDim.x + threadIdx.x;  // 16B-slot granularity
    int total = NB * NT * 260 * 16;
    if (idx >= total) return;
    int slot = idx & 15;
    int pid = idx >> 4;
    int r = pid % 260;
    int bt = pid / 260;
    int hh, ww;
    if (r < 66)       { hh = 0;  ww = r; }
    else if (r < 132) { hh = 65; ww = r - 66; }
    else if (r < 196) { ww = 0;  hh = r - 131; }
    else              { ww = 65; hh = r - 195; }
    size_t p = (((size_t)bt * FT_H + hh) * FT_W + ww) * CIN + slot * 8;
    uint4 z = {0, 0, 0, 0};
    *reinterpret_cast<uint4*>(&fmapT[p]) = z;
}

// ---------------- Kernel 3: transpose+cast fmap -> padded swizzled bf16 ----------------
// fmapT[b][t][h+1][w+1][128ch], channel-group g stored at slot (g&12)|((g&3)^sw_w),
// sw_w = ((w+1)>>1)&3.
__global__ __launch_bounds__(256) void transpose_kernel(
    const float* __restrict__ fmap, unsigned short* __restrict__ fmapT)
{
    __shared__ __attribute__((aligned(16))) unsigned short sT[NW * 136];  // [w][c] pad 136
    int bid = blockIdx.x;
    int h = bid & 63;
    int t = (bid >> 6) & 15;
    int b = bid >> 10;
    int tid = threadIdx.x;

    int c = tid >> 1, wh = (tid & 1) * 32;
    const float* src = fmap + (((size_t)(b * CIN + c) * NT + t) * NH + h) * NW + wh;
    #pragma unroll
    for (int j = 0; j < 8; ++j) {
        float4 v = *reinterpret_cast<const float4*>(src + j * 4);
        int w = wh + j * 4;
        sT[(w + 0) * 136 + c] = f32_to_bf16(v.x);
        sT[(w + 1) * 136 + c] = f32_to_bf16(v.y);
        sT[(w + 2) * 136 + c] = f32_to_bf16(v.z);
        sT[(w + 3) * 136 + c] = f32_to_bf16(v.w);
    }
    __syncthreads();

    int w = tid >> 2, qq = tid & 3;
    int sw = ((w + 1) >> 1) & 3;
    size_t pixbase = (((size_t)(b * NT + t) * FT_H + (h + 1)) * FT_W + (w + 1)) * CIN;
    #pragma unroll
    for (int s = 0; s < 4; ++s) {
        int g = qq * 4 + s;
        uint4 v = *reinterpret_cast<const uint4*>(&sT[w * 136 + g * 8]);
        int slot = (g & 12) | ((g & 3) ^ sw);
        *reinterpret_cast<uint4*>(&fmapT[pixbase + slot * 8]) = v;
    }
}

// ---------------- Kernel 4: implicit-GEMM conv, global_load_lds staged ----------------
// Block: 128 o x (2 t x 4 h x 64 w) outputs. 8 waves, wave = 64 o x 128 pix.
__global__ __launch_bounds__(512, 2) void conv2_kernel(
    const unsigned short* __restrict__ fmapT,
    const unsigned short* __restrict__ wmod,
    float* __restrict__ out)
{
    __shared__ __attribute__((aligned(16))) unsigned short sF[SFPX * 32];   // 110592 B
    __shared__ __attribute__((aligned(16))) unsigned short sW[2][SW_U16];   // 2 x 8192 B

    int obid = blockIdx.x;
    int bid = (obid & 7) * 64 + (obid >> 3);   // XCD-contiguous swizzle (512 % 8 == 0)
    int h0 = (bid & 15) * 4;
    int t0 = ((bid >> 4) & 7) * 2;
    int b  = bid >> 7;

    int tid = threadIdx.x;
    int wv = tid >> 6;
    int l  = tid & 63;
    int lo = l & 15, hi = l >> 4;
    int obase = (wv & 1) * 64;
    int tsub  = (wv >> 1) & 1;
    int hp    = (wv >> 2) * 2;

    int swzA = (lo >> 1) & 3;

    f32x4 acc[4][2][4];
    f32x4 zz = {0.f, 0.f, 0.f, 0.f};
    #pragma unroll
    for (int a = 0; a < 4; ++a)
        #pragma unroll
        for (int h2 = 0; h2 < 2; ++h2)
            #pragma unroll
            for (int p = 0; p < 4; ++p)
                acc[a][h2][p] = zz;

    int nz = (t0 == 0) ? (2 * SFH * SFW * 4) : 0;   // 16B slots of t-planes to zero

    auto stage_f = [&](int ic) {
        #pragma unroll 1
        for (int j = 0; j < 14; ++j) {
            int s = j * 512 + tid;
            if (s < SF_SLOTS) {
                int px = s >> 2, q = s & 3;
                int row = px / SFW;
                int wl = px - row * SFW;
                int tl = row / SFH;
                int hl = row - tl * SFH;
                int ts = t0 + tl - 2; if (ts < 0) ts = 0;       // zeroed later
                int wlc = wl > 65 ? 65 : wl;                    // pad slots, never read
                const unsigned short* src = fmapT +
                    ((((size_t)(b * NT + ts) * FT_H + (h0 + hl)) * FT_W + wlc) << 7)
                    + (ic << 5) + (q << 3);
                gload16(src, &sF[(size_t)s * 8]);
            }
        }
    };
    auto stage_w = [&](int buf, int tap, int ic) {
        const unsigned short* src = wmod +
            (((size_t)(b * NTAP + tap) * COUT + (tid >> 2)) << 7)
            + (ic << 5) + ((tid & 3) << 3);
        gload16(src, &sW[buf][tid * 8]);
    };
    auto zero_t = [&]() {
        uint4 z = {0, 0, 0, 0};
        for (int s = tid; s < nz; s += 512)
            *reinterpret_cast<uint4*>(&sF[s * 8]) = z;
    };

    stage_f(0);
    stage_w(0, 0, 0);
    asm volatile("s_waitcnt vmcnt(0)" ::: "memory");
    if (nz) zero_t();
    __syncthreads();

    int tap = 0, kt = 0, kh = 0, kw = 0, ic = 0;
    for (int ks = 0; ks < 108; ++ks) {
        int cur = ks & 1;
        bool last_tap = (tap == NTAP - 1);
        if (!last_tap)
            stage_w(cur ^ 1, tap + 1, ic);   // async DMA, waited at end of this ks

        int swzB = ((lo + kw) >> 1) & 3;
        const unsigned short* wb = &sW[cur][((obase + lo) << 5) + ((hi ^ swzA) << 3)];
        s16x8 af[4];
        #pragma unroll
        for (int a = 0; a < 4; ++a)
            af[a] = *reinterpret_cast<const s16x8*>(&wb[a << 9]);

        #pragma unroll
        for (int h2 = 0; h2 < 2; ++h2) {
            int row = (tsub + kt) * SFH + hp + h2 + kh;
            int pix = row * SFW + kw + lo;
            const unsigned short* fb = &sF[(pix << 5) + ((hi ^ swzB) << 3)];
            s16x8 bf[4];
            #pragma unroll
            for (int p = 0; p < 4; ++p)
                bf[p] = *reinterpret_cast<const s16x8*>(&fb[p << 9]);
            #pragma unroll
            for (int a = 0; a < 4; ++a)
                #pragma unroll
                for (int p = 0; p < 4; ++p)
                    acc[a][h2][p] = __builtin_amdgcn_mfma_f32_16x16x32_bf16(
                        af[a], bf[p], acc[a][h2][p], 0, 0, 0);
        }

        if (!last_tap) {
            ++tap; ++kw;
            if (kw == 3) { kw = 0; ++kh; if (kh == 3) { kh = 0; ++kt; } }
            asm volatile("s_waitcnt vmcnt(0)" ::: "memory");
            __syncthreads();            // sW[next] landed; everyone done with sW[cur]
        } else {
            __syncthreads();            // all reads of sF done
            if (ks < 107) {
                ++ic;
                stage_f(ic);
                stage_w(cur ^ 1, 0, ic);
                asm volatile("s_waitcnt vmcnt(0)" ::: "memory");
                if (nz) zero_t();
                __syncthreads();
            }
            tap = 0; kw = 0; kh = 0; kt = 0;
        }
    }

    // epilogue: D row = hi*4+reg (o), col = lo (pixel)
    int t = t0 + tsub;
    #pragma unroll
    for (int a = 0; a < 4; ++a) {
        #pragma unroll
        for (int h2 = 0; h2 < 2; ++h2) {
            int h = h0 + hp + h2;
            #pragma unroll
            for (int reg = 0; reg < 4; ++reg) {
                int o = obase + a * 16 + hi * 4 + reg;
                float* orow = out + ((((size_t)b * COUT + o) * NT + t) * NH + h) * NW;
                #pragma unroll
                for (int p = 0; p < 4; ++p)
                    orow[p * 16 + lo] = acc[a][h2][p][reg];
            }
        }
    }
}

// ---------------- Fallback (round-1 conv, used only if ws too small) ----------------
#define HB 4
#define SF_T 3
#define SF_Hf (HB + 2)
#define SF_Wf (NW + 2)
#define IPAD 40
#define SPATf (SF_T * SF_Hf * SF_Wf)

__global__ __launch_bounds__(512) void conv_kernel(
    const float* __restrict__ fmap,
    const unsigned short* __restrict__ wmod,
    float* __restrict__ out)
{
    __shared__ unsigned short sFf[SPATf * IPAD];
    __shared__ unsigned short sWf[2][COUT * IPAD];

    int bid = blockIdx.x;
    int h0 = (bid & 15) * HB;
    int t0 = (bid >> 4) & 15;
    int b  = bid >> 8;

    int tid = threadIdx.x;
    int wv = tid >> 6;
    int l  = tid & 63;
    int lo = l & 15;
    int hi = l >> 4;
    int obase = (wv & 1) * 64;
    int r = wv >> 1;

    int s_ii = tid >> 4;
    int s_ws = tid & 15;

    f32x4 acc[4][4];
    #pragma unroll
    for (int a = 0; a < 4; ++a)
        #pragma unroll
        for (int p = 0; p < 4; ++p)
            acc[a][p] = f32x4{0.f, 0.f, 0.f, 0.f};

    int tap = 0, icc = 0;
    for (int ks = 0; ks < 108; ++ks) {
        if (tap == 0) {
            if (ks) __syncthreads();
            const float* fbase = fmap + (size_t)((b * CIN + icc * 32 + s_ii) * NT) * (NH * NW);
            for (int e = s_ws; e < SPATf; e += 16) {
                int wl = e % SF_Wf;
                int rr = e / SF_Wf;
                int hl = rr % SF_Hf;
                int tl = rr / SF_Hf;
                int ts = t0 + tl - 2;
                int hs = h0 + hl - 1;
                int wsrc = wl - 1;
                float v = 0.f;
                if (ts >= 0 && (unsigned)hs < NH && (unsigned)wsrc < NW)
                    v = fbase[(ts * NH + hs) * NW + wsrc];
                sFf[e * IPAD + s_ii] = f32_to_bf16(v);
            }
            if (ks == 0) {
                int o = tid >> 2, q = tid & 3;
                const unsigned short* src =
                    wmod + (((b * NTAP + 0) * COUT + o) * CIN) + q * 8;
                *reinterpret_cast<uint4*>(&sWf[0][o * IPAD + q * 8]) =
                    *reinterpret_cast<const uint4*>(src);
            }
        }
        __syncthreads();

        if (ks + 1 < 108) {
            int ksn = ks + 1;
            int icn = ksn / 27;
            int tapn = ksn - icn * 27;
            int o = tid >> 2, q = tid & 3;
            const unsigned short* src =
                wmod + (((b * NTAP + tapn) * COUT + o) * CIN) + icn * 32 + q * 8;
            *reinterpret_cast<uint4*>(&sWf[ksn & 1][o * IPAD + q * 8]) =
                *reinterpret_cast<const uint4*>(src);
        }

        int kt = tap / 9;
        int rem = tap - kt * 9;
        int kh = rem / 3;
        int kw = rem - kh * 3;

        s16x8 af[4], bfr[4];
        #pragma unroll
        for (int a = 0; a < 4; ++a) {
            int o = obase + a * 16 + lo;
            af[a] = *reinterpret_cast<const s16x8*>(&sWf[ks & 1][o * IPAD + hi * 8]);
        }
        #pragma unroll
        for (int p = 0; p < 4; ++p) {
            int sp = (kt * SF_Hf + (r + kh)) * SF_Wf + (p * 16 + lo + kw);
            bfr[p] = *reinterpret_cast<const s16x8*>(&sFf[sp * IPAD + hi * 8]);
        }
        #pragma unroll
        for (int a = 0; a < 4; ++a)
            #pragma unroll
            for (int p = 0; p < 4; ++p)
                acc[a][p] = __builtin_amdgcn_mfma_f32_16x16x32_bf16(
                    af[a], bfr[p], acc[a][p], 0, 0, 0);

        if (++tap == 27) { tap = 0; ++icc; }
    }

    int h = h0 + r;
    #pragma unroll
    for (int a = 0; a < 4; ++a) {
        #pragma unroll
        for (int reg = 0; reg < 4; ++reg) {
            int o = obase + a * 16 + hi * 4 + reg;
            float* orow = out + ((((size_t)b * COUT + o) * NT + t0) * NH + h) * NW;
            #pragma unroll
            for (int p = 0; p < 4; ++p)
                orow[p * 16 + lo] = acc[a][p][reg];
        }
    }
}

extern "C" void kernel_launch(void* const* d_in, const int* in_sizes, int n_in,
                              void* d_out, int out_size, void* d_ws, size_t ws_size,
                              hipStream_t stream) {
    (void)in_sizes; (void)n_in; (void)out_size;
    const float* fmap    = (const float*)d_in[0];
    const float* cond    = (const float*)d_in[1];
    const float* weights = (const float*)d_in[2];
    float* outp = (float*)d_out;
    unsigned short* wmod = (unsigned short*)d_ws;

    if (ws_size >= WS_NEED) {
        unsigned short* fmapT = (unsigned short*)((char*)d_ws + WMOD_BYTES);
        modw_kernel<<<dim3(NB * COUT), dim3(256), 0, stream>>>(cond, weights, wmod, 1);
        border_kernel<<<dim3((NB * NT * 260 * 16 + 255) / 256), dim3(256), 0, stream>>>(fmapT);
        transpose_kernel<<<dim3(NB * NT * NH), dim3(256), 0, stream>>>(fmap, fmapT);
        conv2_kernel<<<dim3(NB * (NT / 2) * (NH / 4)), dim3(512), 0, stream>>>(fmapT, wmod, outp);
    } else {
        modw_kernel<<<dim3(NB * COUT), dim3(256), 0, stream>>>(cond, weights, wmod, 0);
        conv_kernel<<<dim3(NB * NT * (NH / HB)), dim3(512), 0, stream>>>(fmap, wmod, outp);
    }
}